// Round 6
// baseline (392.361 us; speedup 1.0000x reference)
//
#include <hip/hip_runtime.h>

// Problem constants (fixed by reference: B=4, C=512, H=W=64, MID=64)
#define BB 4
#define CD 512
#define NP 4096
#define MID 64

typedef _Float16 half8 __attribute__((ext_vector_type(8)));
typedef _Float16 half4 __attribute__((ext_vector_type(4)));
typedef float floatx4 __attribute__((ext_vector_type(4)));
typedef unsigned int uint2v __attribute__((ext_vector_type(2)));
typedef unsigned int uint4v __attribute__((ext_vector_type(4)));

#define LOG2E 1.4426950408889634f

// ---------------------------------------------------------------------------
// Kernel 1: pack wq|wk|wv -> fp16 [640][512], concat biases (fp32 [640]).
// log2(e) folded into wq/bq so softmax uses raw v_exp_f32 (exp2).
// ---------------------------------------------------------------------------
__global__ __launch_bounds__(256) void prep_w(
    const float* __restrict__ wq, const float* __restrict__ wk,
    const float* __restrict__ wv, const float* __restrict__ bq,
    const float* __restrict__ bk, const float* __restrict__ bv,
    _Float16* __restrict__ w_h, float* __restrict__ bias) {
  int idx = blockIdx.x * 256 + threadIdx.x;
  for (int i = idx; i < 640 * 512; i += gridDim.x * 256) {
    int r = i >> 9, c = i & 511;
    float v = (r < 64) ? wq[(r << 9) + c] * LOG2E
            : (r < 128) ? wk[((r - 64) << 9) + c]
                        : wv[((r - 128) << 9) + c];
    w_h[i] = (_Float16)v;
  }
  if (idx < 640) {
    float v = (idx < 64) ? bq[idx] * LOG2E
            : (idx < 128) ? bk[idx - 64]
                          : bv[idx - 128];
    bias[idx] = v;
  }
}

// ---------------------------------------------------------------------------
// Kernel 2: transpose x [b][c][n] fp32 -> xt [b][n][c] fp16 (64x64 LDS tiles)
// ---------------------------------------------------------------------------
__global__ __launch_bounds__(256) void transpose_x(const float* __restrict__ x,
                                                   _Float16* __restrict__ xt) {
  __shared__ float tile[64][65];
  int b = blockIdx.z, c0 = blockIdx.y * 64, n0 = blockIdx.x * 64;
  int t = threadIdx.x;
  const float* xb = x + (size_t)b * CD * NP;
#pragma unroll
  for (int k = 0; k < 16; k++) {
    int cl = k * 4 + (t >> 6);
    int nl = t & 63;
    tile[cl][nl] = xb[(size_t)(c0 + cl) * NP + n0 + nl];
  }
  __syncthreads();
  _Float16* xtb = xt + ((size_t)b * NP + n0) * CD + c0;
#pragma unroll
  for (int k = 0; k < 2; k++) {
    int nl = k * 32 + (t >> 3);
    int cl = (t & 7) * 8;
    half8 pk;
#pragma unroll
    for (int i = 0; i < 8; i++) pk[i] = (_Float16)tile[cl + i][nl];
    *(half8*)(xtb + (size_t)nl * CD + cl) = pk;
  }
}

// ---------------------------------------------------------------------------
// Kernel 3: fused QKV projection, v2. Block = 4 waves, grid (2,64,4):
// rbh picks 320 of the 640 W-rows; 64-position tile staged once in LDS
// (XOR-swizzled 16B units -> conflict-free b128 reads) and shared by all
// waves; wave w computes 80 rows (5 row-tiles x 4 n-tiles, acc=80 VGPR).
// ---------------------------------------------------------------------------
__global__ __launch_bounds__(256, 2) void proj_qkv(
    const _Float16* __restrict__ w_h, const float* __restrict__ bias,
    const _Float16* __restrict__ xt, _Float16* __restrict__ q_h,
    _Float16* __restrict__ k_h, _Float16* __restrict__ v_h) {
  __shared__ _Float16 xls[64 * 512];   // 64 KB, XOR-swizzled 16B units
  int t = threadIdx.x, w = t >> 6, lane = t & 63;
  int col = lane & 15, quad = lane >> 4;
  int rbh = blockIdx.x, nb = blockIdx.y, b = blockIdx.z;
  int n0 = nb * 64;
  const _Float16* xtb = xt + ((size_t)b * NP + n0) * CD;

  // stage xt tile: 16 rounds x 256 threads x 16B; unit u stored at u^(row&7)
#pragma unroll
  for (int j = 0; j < 16; j++) {
    int u = t + j * 256;
    int row = u >> 6, un = u & 63;
    *(half8*)(xls + row * 512 + ((un ^ (row & 7)) << 3)) =
        *(const half8*)(xtb + (size_t)row * CD + un * 8);
  }
  __syncthreads();

  int rw = rbh * 320 + w * 80;        // this wave's first W-row
  floatx4 acc[5][4] = {};
  for (int c = 0; c < CD; c += 32) {
    int cu = c >> 3;                  // base 16B-unit index (multiple of 4)
    half8 a[5], bf[4];
#pragma unroll
    for (int i = 0; i < 5; i++)
      a[i] = *(const half8*)(w_h + (size_t)(rw + i * 16 + col) * CD + c + quad * 8);
#pragma unroll
    for (int j = 0; j < 4; j++) {
      int row = j * 16 + col;
      bf[j] = *(const half8*)(xls + row * 512 + (((cu + quad) ^ (row & 7)) << 3));
    }
#pragma unroll
    for (int i = 0; i < 5; i++)
#pragma unroll
      for (int j = 0; j < 4; j++)
        acc[i][j] = __builtin_amdgcn_mfma_f32_16x16x32_f16(a[i], bf[j], acc[i][j], 0, 0, 0);
  }

#pragma unroll
  for (int i = 0; i < 5; i++) {
    int r0 = rw + i * 16;             // wave-uniform tile base (mult of 16)
    float bi[4];
#pragma unroll
    for (int rr = 0; rr < 4; rr++) bi[rr] = bias[r0 + quad * 4 + rr];
    if (r0 < 128) {
      // q (r0<64) or k: store [n][m] packed half4
      _Float16* dst = (r0 < 64 ? q_h + (size_t)b * NP * MID + r0
                               : k_h + (size_t)b * NP * MID + (r0 - 64));
#pragma unroll
      for (int j = 0; j < 4; j++) {
        int n = n0 + j * 16 + col;
        half4 pk;
#pragma unroll
        for (int rr = 0; rr < 4; rr++) pk[rr] = (_Float16)(acc[i][j][rr] + bi[rr]);
        *(half4*)(dst + (size_t)n * MID + quad * 4) = pk;
      }
    } else {
      int dbase = r0 - 128 + quad * 4;
#pragma unroll
      for (int j = 0; j < 4; j++) {
        int n = n0 + j * 16 + col;
#pragma unroll
        for (int rr = 0; rr < 4; rr++)
          v_h[((size_t)b * CD + dbase + rr) * NP + n] =
              (_Float16)(acc[i][j][rr] + bi[rr]);
      }
    }
  }
}

// ---------------------------------------------------------------------------
// Kernel 4: row max of S (log2-domain). Block = 32 q; 4 waves split the 4096
// keys 4-way; A=K loads amortized over 2 q-tiles. Grid (128, B).
// ---------------------------------------------------------------------------
__global__ __launch_bounds__(256) void rowmax(const _Float16* __restrict__ q_h,
                                              const _Float16* __restrict__ k_h,
                                              float* __restrict__ M) {
  int qb = blockIdx.x, b = blockIdx.y;
  int t = threadIdx.x, w = t >> 6, lane = t & 63;
  int col = lane & 15, quad = lane >> 4;
  int q0 = qb * 32;
  const _Float16* qp = q_h + ((size_t)b * NP + q0) * MID;
  half8 bq[2][2];
#pragma unroll
  for (int qt = 0; qt < 2; qt++)
#pragma unroll
    for (int h = 0; h < 2; h++)
      bq[qt][h] = *(const half8*)(qp + (size_t)(qt * 16 + col) * MID + h * 32 + quad * 8);
  const _Float16* kp = k_h + ((size_t)b * NP + (size_t)w * 1024) * MID;
  float m[2] = {-1e30f, -1e30f};
#pragma unroll 4
  for (int n = 0; n < 1024; n += 16) {
    half8 ak0 = *(const half8*)(kp + (size_t)(n + col) * MID + quad * 8);
    half8 ak1 = *(const half8*)(kp + (size_t)(n + col) * MID + 32 + quad * 8);
#pragma unroll
    for (int qt = 0; qt < 2; qt++) {
      floatx4 s = {};
      s = __builtin_amdgcn_mfma_f32_16x16x32_f16(ak0, bq[qt][0], s, 0, 0, 0);
      s = __builtin_amdgcn_mfma_f32_16x16x32_f16(ak1, bq[qt][1], s, 0, 0, 0);
      m[qt] = fmaxf(m[qt], fmaxf(fmaxf(s[0], s[1]), fmaxf(s[2], s[3])));
    }
  }
  __shared__ float red[4][2][16];
#pragma unroll
  for (int qt = 0; qt < 2; qt++) {
    m[qt] = fmaxf(m[qt], __shfl_xor(m[qt], 16));
    m[qt] = fmaxf(m[qt], __shfl_xor(m[qt], 32));
  }
  if (quad == 0) {
    red[w][0][col] = m[0];
    red[w][1][col] = m[1];
  }
  __syncthreads();
  if (t < 32) {
    int qt = t >> 4, c = t & 15;
    float mm = fmaxf(fmaxf(red[0][qt][c], red[1][qt][c]),
                     fmaxf(red[2][qt][c], red[3][qt][c]));
    M[(size_t)b * NP + q0 + t] = mm;
  }
}

// ---------------------------------------------------------------------------
// Kernel 5: attention + PV + epilogue, v10 (BARRIER-FREE independent waves).
// Grid 512 = b(4) x ds(2) x qb(64); block = 4 waves = 64q x 256d.
// r0-r5 post-mortem: every scheduled variant (v4/v6/v7/v9) compiled to the
// same ~6.3K cyc/chunk because the per-chunk cross-wave P exchange
// (LDS+barrier) creates scheduling regions hipcc flattens. v10 REMOVES the
// exchange: each wave redundantly scores the full 64q x 64k block (loads
// all 64 keys' K; +24 MFMA/wave/chunk) and keeps P in-register. The score
// C-frag (lane: P[key=kf*16+quad*4+r][q=col]) is rearranged to the PV
// B-frag layout (lane: P[k=kb*32+quad*8+j][q=col]) with ds_bpermute:
//   k = kf*16 + q4*4 + rr, kf = 2kb+(quad>>1), q4 = (quad&1)*2+(j2>>1),
//   word = j2&1; pull both kf candidates from lane col+16*q4, select by
//   quad>>1. NO barriers, NO __shared__, NO __syncthreads: 8 independent
//   waves/CU self-hide latency; l reduced per-wave via shfl_xor (every
//   wave sees all keys). L2 check: 64 b128/block/chunk = 2.1 GB ~ 23 TB/s
//   at 90 us, under the 34.5 TB/s ceiling.
// ---------------------------------------------------------------------------
__global__ __launch_bounds__(256, 2) void attn_pv(
    const _Float16* __restrict__ q_h, const _Float16* __restrict__ k_h,
    const _Float16* __restrict__ v_h, const float* __restrict__ M,
    const float* __restrict__ x, const float* __restrict__ alpha_p,
    float* __restrict__ out) {
  int bid = blockIdx.x;
  int combo = bid & 7;               // -> XCD via round-robin dispatch
  int b = combo >> 1, ds = combo & 1;
  int qb = bid >> 3;                 // 0..63
  int q0 = qb * 64, d0 = ds * 256;

  int t = threadIdx.x, w = t >> 6, lane = t & 63;
  int col = lane & 15, quad = lane >> 4;

  const _Float16* qp = q_h + ((size_t)b * NP + q0) * MID;
  half8 bq[4][2];
#pragma unroll
  for (int qt = 0; qt < 4; qt++)
#pragma unroll
    for (int h = 0; h < 2; h++)
      bq[qt][h] = *(const half8*)(qp + (size_t)(qt * 16 + col) * MID + h * 32 + quad * 8);
  float Mq[4];
#pragma unroll
  for (int qt = 0; qt < 4; qt++) Mq[qt] = M[(size_t)b * NP + q0 + qt * 16 + col];

  const _Float16* kp = k_h + (size_t)b * NP * MID;               // all keys
  const _Float16* vp = v_h + ((size_t)(b * CD + d0) + w * 64) * NP;
  float alpha = alpha_p[0];

  floatx4 acc[4][4] = {};            // [dt][qt] = 64 VGPRs, static indices
  float lp[4] = {0.f, 0.f, 0.f, 0.f};

  // bpermute source byte-addrs: q4 = (quad&1)*2 + (j2>>1)
  int src_lo = (col + 16 * ((quad & 1) * 2)) << 2;   // j2 = 0,1
  int src_hi = src_lo + (16 << 2);                   // j2 = 2,3
  int hiSel = quad & 2;                              // kf select: quad>=2

  for (int ci = 0; ci < 64; ci++) {
    int nc = ci * 64;

    // K: ALL 64 keys of this chunk (8 x b128)
    half8 ak[4][2];
#pragma unroll
    for (int kf = 0; kf < 4; kf++) {
      const _Float16* kr = kp + (size_t)(nc + kf * 16 + col) * MID + quad * 8;
      ak[kf][0] = *(const half8*)(kr);
      ak[kf][1] = *(const half8*)(kr + 32);
    }
    // V: own 64-d slice (8 x b128)
    half8 av[2][4];
#pragma unroll
    for (int kb = 0; kb < 2; kb++)
#pragma unroll
      for (int dt = 0; dt < 4; dt++)
        av[kb][dt] = *(const half8*)(vp + (size_t)(dt * 16 + col) * NP + nc + kb * 32 + quad * 8);

#pragma unroll
    for (int qt = 0; qt < 4; qt++) {
      // scores: all 64 keys vs this 16-q tile; exp in log2 domain
      uint2v pw[4];
#pragma unroll
      for (int kf = 0; kf < 4; kf++) {
        floatx4 s = {};
        s = __builtin_amdgcn_mfma_f32_16x16x32_f16(ak[kf][0], bq[qt][0], s, 0, 0, 0);
        s = __builtin_amdgcn_mfma_f32_16x16x32_f16(ak[kf][1], bq[qt][1], s, 0, 0, 0);
        half4 pk;
#pragma unroll
        for (int r = 0; r < 4; r++) {
          float p = __builtin_amdgcn_exp2f(s[r] - Mq[qt]);
          lp[qt] += p;
          pk[r] = (_Float16)p;
        }
        pw[kf] = __builtin_bit_cast(uint2v, pk);
      }
      // in-wave rearrange (score layout -> PV B-frag layout) + PV
#pragma unroll
      for (int kb = 0; kb < 2; kb++) {
        unsigned int wv0, wv1, wv2, wv3;
        {
          int a0 = __builtin_amdgcn_ds_bpermute(src_lo, (int)pw[2 * kb][0]);
          int b0 = __builtin_amdgcn_ds_bpermute(src_lo, (int)pw[2 * kb + 1][0]);
          wv0 = hiSel ? b0 : a0;
          int a1 = __builtin_amdgcn_ds_bpermute(src_lo, (int)pw[2 * kb][1]);
          int b1 = __builtin_amdgcn_ds_bpermute(src_lo, (int)pw[2 * kb + 1][1]);
          wv1 = hiSel ? b1 : a1;
          int a2 = __builtin_amdgcn_ds_bpermute(src_hi, (int)pw[2 * kb][0]);
          int b2 = __builtin_amdgcn_ds_bpermute(src_hi, (int)pw[2 * kb + 1][0]);
          wv2 = hiSel ? b2 : a2;
          int a3 = __builtin_amdgcn_ds_bpermute(src_hi, (int)pw[2 * kb][1]);
          int b3 = __builtin_amdgcn_ds_bpermute(src_hi, (int)pw[2 * kb + 1][1]);
          wv3 = hiSel ? b3 : a3;
        }
        uint4v wvv = {wv0, wv1, wv2, wv3};
        half8 bp = __builtin_bit_cast(half8, wvv);
#pragma unroll
        for (int dt = 0; dt < 4; dt++)
          acc[dt][qt] = __builtin_amdgcn_mfma_f32_16x16x32_f16(av[kb][dt], bp, acc[dt][qt], 0, 0, 0);
      }
    }
  }

  // per-wave softmax denominator: each wave saw ALL keys; quad-reduce
  float linv[4];
#pragma unroll
  for (int qt = 0; qt < 4; qt++) {
    lp[qt] += __shfl_xor(lp[qt], 16);
    lp[qt] += __shfl_xor(lp[qt], 32);
    linv[qt] = alpha / lp[qt];
  }

  // epilogue: fused alpha/l scale + residual; 64B-segment coalesced stores
  const float* xp = x + ((size_t)(b * CD + d0) + w * 64) * NP;
  float* op = out + ((size_t)(b * CD + d0) + w * 64) * NP;
#pragma unroll
  for (int dt = 0; dt < 4; dt++)
#pragma unroll
    for (int qt = 0; qt < 4; qt++) {
#pragma unroll
      for (int r = 0; r < 4; r++) {
        size_t o = (size_t)(dt * 16 + quad * 4 + r) * NP + q0 + qt * 16 + col;
        op[o] = acc[dt][qt][r] * linv[qt] + xp[o];
      }
    }
}

// ---------------------------------------------------------------------------
extern "C" void kernel_launch(void* const* d_in, const int* in_sizes, int n_in,
                              void* d_out, int out_size, void* d_ws, size_t ws_size,
                              hipStream_t stream) {
  const float* x     = (const float*)d_in[0];
  const float* wq    = (const float*)d_in[1];
  const float* bq    = (const float*)d_in[2];
  const float* wk    = (const float*)d_in[3];
  const float* bk    = (const float*)d_in[4];
  const float* wv    = (const float*)d_in[5];
  const float* bv    = (const float*)d_in[6];
  const float* alpha = (const float*)d_in[7];
  float* out = (float*)d_out;

  char* ws = (char*)d_ws;
  _Float16* w_h  = (_Float16*)(ws);                    // 640*512*2   = 655360
  float*    bias = (float*)(ws + 655360);              // 640*4       = 2560
  float*    Mbuf = (float*)(ws + 657920);              // 4*4096*4    = 65536
  _Float16* xt   = (_Float16*)(ws + 723456);           // 4*4096*512*2= 16777216
  _Float16* q_h  = (_Float16*)(ws + 17500672);         // 4*4096*64*2 = 2097152
  _Float16* k_h  = (_Float16*)(ws + 19597824);         // 4*4096*64*2 = 2097152
  _Float16* v_h  = (_Float16*)(ws + 21694976);         // 4*512*4096*2= 16777216

  prep_w<<<1280, 256, 0, stream>>>(wq, wk, wv, bq, bk, bv, w_h, bias);
  transpose_x<<<dim3(64, 8, BB), 256, 0, stream>>>(x, xt);
  proj_qkv<<<dim3(2, 64, BB), 256, 0, stream>>>(w_h, bias, xt, q_h, k_h, v_h);
  rowmax<<<dim3(128, BB), 256, 0, stream>>>(q_h, k_h, Mbuf);
  attn_pv<<<512, 256, 0, stream>>>(q_h, k_h, v_h, Mbuf, x, alpha, out);
}

// Round 7
// 254.751 us; speedup vs baseline: 1.5402x; 1.5402x over previous
//
#include <hip/hip_runtime.h>

// Problem constants (fixed by reference: B=4, C=512, H=W=64, MID=64)
#define BB 4
#define CD 512
#define NP 4096
#define MID 64

typedef _Float16 half8 __attribute__((ext_vector_type(8)));
typedef _Float16 half4 __attribute__((ext_vector_type(4)));
typedef float floatx4 __attribute__((ext_vector_type(4)));

#define LOG2E 1.4426950408889634f

// ---------------------------------------------------------------------------
// Kernel 1: pack wq|wk|wv -> fp16 [640][512], concat biases (fp32 [640]).
// ---------------------------------------------------------------------------
__global__ __launch_bounds__(256) void prep_w(
    const float* __restrict__ wq, const float* __restrict__ wk,
    const float* __restrict__ wv, const float* __restrict__ bq,
    const float* __restrict__ bk, const float* __restrict__ bv,
    _Float16* __restrict__ w_h, float* __restrict__ bias) {
  int idx = blockIdx.x * 256 + threadIdx.x;
  for (int i = idx; i < 640 * 512; i += gridDim.x * 256) {
    int r = i >> 9, c = i & 511;
    float v = (r < 64) ? wq[(r << 9) + c] * LOG2E
            : (r < 128) ? wk[((r - 64) << 9) + c]
                        : wv[((r - 128) << 9) + c];
    w_h[i] = (_Float16)v;
  }
  if (idx < 640) {
    float v = (idx < 64) ? bq[idx] * LOG2E
            : (idx < 128) ? bk[idx - 64]
                          : bv[idx - 128];
    bias[idx] = v;
  }
}

// ---------------------------------------------------------------------------
// Kernel 2: transpose x [b][c][n] fp32 -> xt [b][n][c] fp16 (64x64 LDS tiles)
// ---------------------------------------------------------------------------
__global__ __launch_bounds__(256) void transpose_x(const float* __restrict__ x,
                                                   _Float16* __restrict__ xt) {
  __shared__ float tile[64][65];
  int b = blockIdx.z, c0 = blockIdx.y * 64, n0 = blockIdx.x * 64;
  int t = threadIdx.x;
  const float* xb = x + (size_t)b * CD * NP;
#pragma unroll
  for (int k = 0; k < 16; k++) {
    int cl = k * 4 + (t >> 6);
    int nl = t & 63;
    tile[cl][nl] = xb[(size_t)(c0 + cl) * NP + n0 + nl];
  }
  __syncthreads();
  _Float16* xtb = xt + ((size_t)b * NP + n0) * CD + c0;
#pragma unroll
  for (int k = 0; k < 2; k++) {
    int nl = k * 32 + (t >> 3);
    int cl = (t & 7) * 8;
    half8 pk;
#pragma unroll
    for (int i = 0; i < 8; i++) pk[i] = (_Float16)tile[cl + i][nl];
    *(half8*)(xtb + (size_t)nl * CD + cl) = pk;
  }
}

// ---------------------------------------------------------------------------
// Kernel 3: fused QKV projection (unchanged).
// ---------------------------------------------------------------------------
__global__ __launch_bounds__(256, 2) void proj_qkv(
    const _Float16* __restrict__ w_h, const float* __restrict__ bias,
    const _Float16* __restrict__ xt, _Float16* __restrict__ q_h,
    _Float16* __restrict__ k_h, _Float16* __restrict__ v_h) {
  __shared__ _Float16 xls[64 * 512];   // 64 KB, XOR-swizzled 16B units
  int t = threadIdx.x, w = t >> 6, lane = t & 63;
  int col = lane & 15, quad = lane >> 4;
  int rbh = blockIdx.x, nb = blockIdx.y, b = blockIdx.z;
  int n0 = nb * 64;
  const _Float16* xtb = xt + ((size_t)b * NP + n0) * CD;
#pragma unroll
  for (int j = 0; j < 16; j++) {
    int u = t + j * 256;
    int row = u >> 6, un = u & 63;
    *(half8*)(xls + row * 512 + ((un ^ (row & 7)) << 3)) =
        *(const half8*)(xtb + (size_t)row * CD + un * 8);
  }
  __syncthreads();

  int rw = rbh * 320 + w * 80;
  floatx4 acc[5][4] = {};
  for (int c = 0; c < CD; c += 32) {
    int cu = c >> 3;
    half8 a[5], bf[4];
#pragma unroll
    for (int i = 0; i < 5; i++)
      a[i] = *(const half8*)(w_h + (size_t)(rw + i * 16 + col) * CD + c + quad * 8);
#pragma unroll
    for (int j = 0; j < 4; j++) {
      int row = j * 16 + col;
      bf[j] = *(const half8*)(xls + row * 512 + (((cu + quad) ^ (row & 7)) << 3));
    }
#pragma unroll
    for (int i = 0; i < 5; i++)
#pragma unroll
      for (int j = 0; j < 4; j++)
        acc[i][j] = __builtin_amdgcn_mfma_f32_16x16x32_f16(a[i], bf[j], acc[i][j], 0, 0, 0);
  }

#pragma unroll
  for (int i = 0; i < 5; i++) {
    int r0 = rw + i * 16;
    float bi[4];
#pragma unroll
    for (int rr = 0; rr < 4; rr++) bi[rr] = bias[r0 + quad * 4 + rr];
    if (r0 < 128) {
      _Float16* dst = (r0 < 64 ? q_h + (size_t)b * NP * MID + r0
                               : k_h + (size_t)b * NP * MID + (r0 - 64));
#pragma unroll
      for (int j = 0; j < 4; j++) {
        int n = n0 + j * 16 + col;
        half4 pk;
#pragma unroll
        for (int rr = 0; rr < 4; rr++) pk[rr] = (_Float16)(acc[i][j][rr] + bi[rr]);
        *(half4*)(dst + (size_t)n * MID + quad * 4) = pk;
      }
    } else {
      int dbase = r0 - 128 + quad * 4;
#pragma unroll
      for (int j = 0; j < 4; j++) {
        int n = n0 + j * 16 + col;
#pragma unroll
        for (int rr = 0; rr < 4; rr++)
          v_h[((size_t)b * CD + dbase + rr) * NP + n] =
              (_Float16)(acc[i][j][rr] + bi[rr]);
      }
    }
  }
}

// ---------------------------------------------------------------------------
// Kernel 4: row max of S (unchanged).
// ---------------------------------------------------------------------------
__global__ __launch_bounds__(256) void rowmax(const _Float16* __restrict__ q_h,
                                              const _Float16* __restrict__ k_h,
                                              float* __restrict__ M) {
  int qb = blockIdx.x, b = blockIdx.y;
  int t = threadIdx.x, w = t >> 6, lane = t & 63;
  int col = lane & 15, quad = lane >> 4;
  int q0 = qb * 32;
  const _Float16* qp = q_h + ((size_t)b * NP + q0) * MID;
  half8 bq[2][2];
#pragma unroll
  for (int qt = 0; qt < 2; qt++)
#pragma unroll
    for (int h = 0; h < 2; h++)
      bq[qt][h] = *(const half8*)(qp + (size_t)(qt * 16 + col) * MID + h * 32 + quad * 8);
  const _Float16* kp = k_h + ((size_t)b * NP + (size_t)w * 1024) * MID;
  float m[2] = {-1e30f, -1e30f};
#pragma unroll 4
  for (int n = 0; n < 1024; n += 16) {
    half8 ak0 = *(const half8*)(kp + (size_t)(n + col) * MID + quad * 8);
    half8 ak1 = *(const half8*)(kp + (size_t)(n + col) * MID + 32 + quad * 8);
#pragma unroll
    for (int qt = 0; qt < 2; qt++) {
      floatx4 s = {};
      s = __builtin_amdgcn_mfma_f32_16x16x32_f16(ak0, bq[qt][0], s, 0, 0, 0);
      s = __builtin_amdgcn_mfma_f32_16x16x32_f16(ak1, bq[qt][1], s, 0, 0, 0);
      m[qt] = fmaxf(m[qt], fmaxf(fmaxf(s[0], s[1]), fmaxf(s[2], s[3])));
    }
  }
  __shared__ float red[4][2][16];
#pragma unroll
  for (int qt = 0; qt < 2; qt++) {
    m[qt] = fmaxf(m[qt], __shfl_xor(m[qt], 16));
    m[qt] = fmaxf(m[qt], __shfl_xor(m[qt], 32));
  }
  if (quad == 0) {
    red[w][0][col] = m[0];
    red[w][1][col] = m[1];
  }
  __syncthreads();
  if (t < 32) {
    int qt = t >> 4, c = t & 15;
    float mm = fmaxf(fmaxf(red[0][qt][c], red[1][qt][c]),
                     fmaxf(red[2][qt][c], red[3][qt][c]));
    M[(size_t)b * NP + q0 + t] = mm;
  }
}

// ---------------------------------------------------------------------------
// Kernel 5: attention + PV + epilogue, v11 (LDS-DMA pipeline).
// Grid 512 = b(4) x ds(2) x qb(64); block = 4 waves = 64q x 256d.
// r1-r6 model: per-block-chunk cost is a ~3K-cycle invariant because the
// register allocator (VGPR 124-128) batches the 10 K/V loads 2-3 at a time
// -> 4-5 serial L2 round trips per chunk; every source pipeline collapses.
// v11 removes registers from staging: global_load_lds_dwordx4 DMA (no dest
// VGPR -> nothing to sink) into double-buffered LDS, one chunk ahead, with
// COUNTED vmcnt waits (10/6/6, never 0). K/V LDS regions are WAVE-PRIVATE
// (each wave DMAs and reads only its own section) -> no barrier for K/V;
// only P needs the 2 lgkm-only barriers/chunk. V staged in 32-key halves.
// LDS map (50432 B total, 2 blocks/CU):
//   vbuf [2][16384]  half-chunk V, buffer index = half parity h
//   kbuf [2][8192]   K chunks (swizzled); P(ci) overwrites kbuf[ci&1]
//   lred 1024, lfin 256
// Per chunk: [lgkm+bar A] DMA K(ci+1) | vmcnt(10) | score(ci) -> P |
// [lgkm+bar B] vmcnt(6) | PV h0 | DMA Vh0(ci+1) | vmcnt(6) | PV h1 |
// DMA Vh1(ci+1).  Steady-state outstanding trace verified: 10/12->10/6/10/6/10.
// ---------------------------------------------------------------------------
#define DMA16(gp, ldsoff)                                                      \
  asm volatile("s_mov_b32 m0, %0\n\t"                                         \
               "global_load_lds_dwordx4 %1, off"                              \
               :: "s"(__builtin_amdgcn_readfirstlane((int)(ldsoff))),          \
                  "v"(gp)                                                      \
               : "memory")

__global__ __launch_bounds__(256, 2) void attn_pv(
    const _Float16* __restrict__ q_h, const _Float16* __restrict__ k_h,
    const _Float16* __restrict__ v_h, const float* __restrict__ M,
    const float* __restrict__ x, const float* __restrict__ alpha_p,
    float* __restrict__ out) {
  int bid = blockIdx.x;
  int combo = bid & 7;               // -> XCD via round-robin dispatch
  int b = combo >> 1, ds = combo & 1;
  int qb = bid >> 3;                 // 0..63
  int q0 = qb * 64, d0 = ds * 256;

  int t = threadIdx.x, w = t >> 6, lane = t & 63;
  int col = lane & 15, quad = lane >> 4;
  int c7 = col & 7;

  __shared__ floatx4 smem4[50432 / 16];
  char* smem = (char*)smem4;
  char* vbufB = smem;                    // 2 x 16384
  char* kbufB = smem + 32768;            // 2 x 8192
  float* lred = (float*)(smem + 49152);  // [4][4][16]
  float* lfin = (float*)(smem + 50176);  // [64]

  const _Float16* qp = q_h + ((size_t)b * NP + q0) * MID;
  half8 bq[4][2];
#pragma unroll
  for (int qt = 0; qt < 4; qt++)
#pragma unroll
    for (int h = 0; h < 2; h++)
      bq[qt][h] = *(const half8*)(qp + (size_t)(qt * 16 + col) * MID + h * 32 + quad * 8);
  float Mq[4];
#pragma unroll
  for (int qt = 0; qt < 4; qt++) Mq[qt] = M[(size_t)b * NP + q0 + qt * 16 + col];

  // per-lane DMA source offsets (in halves), constant across chunks:
  // K: slot = lane -> key-local (lane>>3), stored d-unit (lane&7) holds
  //    logical unit (lane&7)^((lane>>3)&7)  [XOR swizzle, involution]
  int klane = (lane >> 3) * MID + (((lane & 7) ^ ((lane >> 3) & 7)) << 3);
  // V: slot = lane -> d-row (lane>>2), k-unit (lane&3), linear (no swizzle:
  //    64B row stride is bank-even for the quad-indexed b128 reads)
  size_t vlane = (size_t)(lane >> 2) * NP + ((lane & 3) << 3);

  const _Float16* kgb = k_h + (size_t)b * NP * MID;
  const _Float16* vgb = v_h + (size_t)(b * CD + d0 + w * 64) * NP;

  floatx4 acc[4][4] = {};            // [dt][qt] = 64 VGPRs, static indices
  float lp[4] = {0.f, 0.f, 0.f, 0.f};

  int kdw = 32768 + w * 2048;        // kbuf wave base (LDS bytes)
  int vdw = w * 4096;                // vbuf wave base

  // ---- prologue DMAs (order: K(0) x2, Vh0(0) x4, Vh1(0) x4) ----
#pragma unroll
  for (int j = 0; j < 2; j++)
    DMA16(kgb + (size_t)(0 + w * 16 + j * 8) * MID + klane, kdw + j * 1024);
#pragma unroll
  for (int h = 0; h < 2; h++)
#pragma unroll
    for (int j = 0; j < 4; j++)
      DMA16(vgb + (size_t)(j * 16) * NP + h * 32 + vlane,
            h * 16384 + vdw + j * 1024);

  for (int ci = 0; ci < 64; ci++) {
    int p = ci & 1;
    int nxt = ((ci + 1) & 63) * 64;

    // [A] drain own ds reads; all waves' P(ci-1) reads retired -> kbuf[1-p]
    // free for K(ci+1) DMA.
    asm volatile("s_waitcnt lgkmcnt(0)\n\ts_barrier" ::: "memory");
#pragma unroll
    for (int j = 0; j < 2; j++)
      DMA16(kgb + (size_t)(nxt + w * 16 + j * 8) * MID + klane,
            kdw + (1 - p) * 8192 + j * 1024);

    // K(ci) landed (own-wave data): 10 newest stay in flight.
    asm volatile("s_waitcnt vmcnt(10)" ::: "memory");

    // ---- score: own 16 keys vs 64 q; K from LDS (swizzled) ----
    const char* kb = kbufB + p * 8192 + w * 2048;
    int sl0 = quad ^ c7;
    half8 ak0 = *(const half8*)(kb + col * 128 + (sl0 << 4));
    half8 ak1 = *(const half8*)(kb + col * 128 + ((sl0 ^ 4) << 4));
    char* pbW = kbufB + p * 8192;    // P overwrites the K chunk buffer
#pragma unroll
    for (int qt = 0; qt < 4; qt++) {
      floatx4 s = {};
      s = __builtin_amdgcn_mfma_f32_16x16x32_f16(ak0, bq[qt][0], s, 0, 0, 0);
      s = __builtin_amdgcn_mfma_f32_16x16x32_f16(ak1, bq[qt][1], s, 0, 0, 0);
      half4 pk;
#pragma unroll
      for (int r = 0; r < 4; r++) {
        float pv = __builtin_amdgcn_exp2f(s[r] - Mq[qt]);
        lp[qt] += pv;
        pk[r] = (_Float16)pv;
      }
      // P[q][kk] in own 2KB section: row q = qt*16+col, kk base quad*4
      *(half4*)(pbW + w * 2048 + (qt * 16 + col) * 32 + quad * 8) = pk;
    }

    // [B] P(ci) published
    asm volatile("s_waitcnt lgkmcnt(0)\n\ts_barrier" ::: "memory");

#pragma unroll
    for (int h = 0; h < 2; h++) {
      // Vh(2ci+h) landed: 6 newest stay in flight.
      asm volatile("s_waitcnt vmcnt(6)" ::: "memory");
      // P B-frags: section = 2h + (quad>>1), kk offset (quad&1)*8
      half8 bp[4];
#pragma unroll
      for (int qt = 0; qt < 4; qt++)
        bp[qt] = *(const half8*)(pbW + (2 * h + (quad >> 1)) * 2048 +
                                 (qt * 16 + col) * 32 + ((quad & 1) << 4));
      // V A-frags from own vbuf section (linear, bank-even)
      const char* vb = vbufB + h * 16384 + vdw;
      half8 av[4];
#pragma unroll
      for (int dt = 0; dt < 4; dt++)
        av[dt] = *(const half8*)(vb + (dt * 16 + col) * 64 + (quad << 4));
      __builtin_amdgcn_s_setprio(1);
#pragma unroll
      for (int dt = 0; dt < 4; dt++)
#pragma unroll
        for (int qt = 0; qt < 4; qt++)
          acc[dt][qt] = __builtin_amdgcn_mfma_f32_16x16x32_f16(av[dt], bp[qt], acc[dt][qt], 0, 0, 0);
      __builtin_amdgcn_s_setprio(0);
      // refill this half's buffer for chunk ci+1 (wave-private region)
#pragma unroll
      for (int j = 0; j < 4; j++)
        DMA16(vgb + (size_t)(j * 16) * NP + nxt + h * 32 + vlane,
              h * 16384 + vdw + j * 1024);
    }
  }

  // l: lane's partial covers its quad's 4 keys of this wave's sections
#pragma unroll
  for (int qt = 0; qt < 4; qt++) {
    lp[qt] += __shfl_xor(lp[qt], 16);
    lp[qt] += __shfl_xor(lp[qt], 32);
    if (quad == 0) lred[(w * 4 + qt) * 16 + col] = lp[qt];
  }
  __syncthreads();
  if (t < 64) {
    int qt = t >> 4, c = t & 15;
    float l = lred[(0 + qt) * 16 + c] + lred[(4 + qt) * 16 + c] +
              lred[(8 + qt) * 16 + c] + lred[(12 + qt) * 16 + c];
    lfin[t] = alpha_p[0] / l;
  }
  __syncthreads();

  // epilogue: fused alpha/l scale + residual; 64B-segment coalesced stores
  const float* xp = x + ((size_t)(b * CD + d0) + w * 64) * NP;
  float* op = out + ((size_t)(b * CD + d0) + w * 64) * NP;
#pragma unroll
  for (int dt = 0; dt < 4; dt++)
#pragma unroll
    for (int qt = 0; qt < 4; qt++) {
      float linv = lfin[qt * 16 + col];
#pragma unroll
      for (int r = 0; r < 4; r++) {
        size_t o = (size_t)(dt * 16 + quad * 4 + r) * NP + q0 + qt * 16 + col;
        op[o] = acc[dt][qt][r] * linv + xp[o];
      }
    }
}

// ---------------------------------------------------------------------------
extern "C" void kernel_launch(void* const* d_in, const int* in_sizes, int n_in,
                              void* d_out, int out_size, void* d_ws, size_t ws_size,
                              hipStream_t stream) {
  const float* x     = (const float*)d_in[0];
  const float* wq    = (const float*)d_in[1];
  const float* bq    = (const float*)d_in[2];
  const float* wk    = (const float*)d_in[3];
  const float* bk    = (const float*)d_in[4];
  const float* wv    = (const float*)d_in[5];
  const float* bv    = (const float*)d_in[6];
  const float* alpha = (const float*)d_in[7];
  float* out = (float*)d_out;

  char* ws = (char*)d_ws;
  _Float16* w_h  = (_Float16*)(ws);                    // 640*512*2   = 655360
  float*    bias = (float*)(ws + 655360);              // 640*4       = 2560
  float*    Mbuf = (float*)(ws + 657920);              // 4*4096*4    = 65536
  _Float16* xt   = (_Float16*)(ws + 723456);           // 4*4096*512*2= 16777216
  _Float16* q_h  = (_Float16*)(ws + 17500672);         // 4*4096*64*2 = 2097152
  _Float16* k_h  = (_Float16*)(ws + 19597824);         // 4*4096*64*2 = 2097152
  _Float16* v_h  = (_Float16*)(ws + 21694976);         // 4*512*4096*2= 16777216

  prep_w<<<1280, 256, 0, stream>>>(wq, wk, wv, bq, bk, bv, w_h, bias);
  transpose_x<<<dim3(64, 8, BB), 256, 0, stream>>>(x, xt);
  proj_qkv<<<dim3(2, 64, BB), 256, 0, stream>>>(w_h, bias, xt, q_h, k_h, v_h);
  rowmax<<<dim3(128, BB), 256, 0, stream>>>(q_h, k_h, Mbuf);
  attn_pv<<<512, 256, 0, stream>>>(q_h, k_h, v_h, Mbuf, x, alpha, out);
}